// Round 13
// baseline (195.125 us; speedup 1.0000x reference)
//
#include <hip/hip_runtime.h>
#include <stdint.h>

#define S_LEN 2048
#define DMODEL 2048
#define NH 32
#define NKV 8
#define HD 64

typedef __attribute__((ext_vector_type(8))) __bf16 bf16x8;
typedef __attribute__((ext_vector_type(4))) float f32x4;
typedef __attribute__((ext_vector_type(16))) float f32x16;

__device__ __forceinline__ unsigned short f2bf(float f) {
    union { float f; uint32_t u; } v; v.f = f;
    uint32_t u = v.u;
    u += 0x7FFFu + ((u >> 16) & 1u);
    return (unsigned short)(u >> 16);
}

__device__ __forceinline__ float bf2f(unsigned short b) {
    union { uint32_t u; float f; } v;
    v.u = ((uint32_t)b) << 16;
    return v.f;
}

__device__ __forceinline__ uint32_t cvt_pk_bf16(float lo, float hi) {
    uint32_t r;
    asm("v_cvt_pk_bf16_f32 %0, %1, %2" : "=v"(r) : "v"(lo), "v"(hi));
    return r;
}

#define GLDS16(g, l)                                                          \
    __builtin_amdgcn_global_load_lds(                                         \
        (const __attribute__((address_space(1))) unsigned int*)(g),           \
        (__attribute__((address_space(3))) unsigned int*)(l), 16, 0, 0)

// 40 units/head: every strip chunked into 8-tile KV-chunks, longest-first.
// len-8 x28, then len-6 x4, len-4 x4, len-2 x4.
__device__ const int8_t kUQT[40] = {3,4,5,6,7,7,8,8,9,9,10,10,11,11,11,12,12,12,13,13,13,14,14,14,15,15,15,15,
                                    2,6,10,14, 1,5,9,13, 0,4,8,12};
__device__ const int8_t kUCH[40] = {0,0,0,0,0,1,0,1,0,1,0,1,0,1,2,0,1,2,0,1,2,0,1,2,0,1,2,3,
                                    0,1,2,3, 0,1,2,3, 0,1,2,3};

__device__ __forceinline__ int slot_base(int qt) {  // strips qt>=4 only
    return (qt < 8) ? (qt - 4) * 2 : (qt < 12) ? 8 + (qt - 8) * 3
                                               : 20 + (qt - 12) * 4;
}

// ---------------- elementwise cast fp32 -> bf16 ----------------
__global__ void cast_bf16_kernel(const float* __restrict__ src,
                                 unsigned short* __restrict__ dst, int n) {
    int g = (blockIdx.x * blockDim.x + threadIdx.x) * 8;
    if (g >= n) return;
    float4 a = *(const float4*)&src[g];
    float4 b = *(const float4*)&src[g + 4];
    unsigned short o[8];
    o[0] = f2bf(a.x); o[1] = f2bf(a.y); o[2] = f2bf(a.z); o[3] = f2bf(a.w);
    o[4] = f2bf(b.x); o[5] = f2bf(b.y); o[6] = f2bf(b.z); o[7] = f2bf(b.w);
    *(uint4*)&dst[g] = *(const uint4*)o;
}

// ---------------- tiled transpose + cast: dst[c][r] = bf16(src[r][c]) ------
__global__ void transpose_cast_kernel(const float* __restrict__ src,
                                      unsigned short* __restrict__ dst,
                                      int R, int C) {
    __shared__ float tile[32][33];
    int c0 = blockIdx.x * 32, r0 = blockIdx.y * 32;
    int tx = threadIdx.x, ty = threadIdx.y;
#pragma unroll
    for (int i = 0; i < 32; i += 8)
        tile[ty + i][tx] = src[(size_t)(r0 + ty + i) * C + c0 + tx];
    __syncthreads();
#pragma unroll
    for (int i = 0; i < 32; i += 8)
        dst[(size_t)(c0 + ty + i) * R + r0 + tx] = f2bf(tile[tx][ty + i]);
}

// ---- 128x64-tile triple-buffered counted-vmcnt bf16 GEMM (T3/T4 + T1) -----
template <bool BF16OUT>
__global__ __launch_bounds__(256) void gemm_bt_kernel(
    const unsigned short* __restrict__ A, const unsigned short* __restrict__ BT,
    float* __restrict__ C0, unsigned short* __restrict__ Cb,
    int M, int N, int K) {
    __shared__ unsigned short As[3][128 * 32];
    __shared__ unsigned short Bs[3][64 * 32];
    const int t = threadIdx.x;
    const int lane = t & 63, wave = t >> 6;
    const int wr = wave >> 1, wc = wave & 1;
    const int gx = gridDim.x;
    const int nwg = gx * gridDim.y;
    const int wg = blockIdx.y * gx + blockIdx.x;
    const int swz = (wg & 7) * (nwg >> 3) + (wg >> 3);
    const int m0 = (swz % gx) * 128, n0 = (swz / gx) * 64;
    const int l15 = lane & 15, lhi = lane >> 4;
    f32x4 acc[4][2] = {};
    const unsigned short* ga = A + (size_t)(m0 + (t >> 2)) * K + (t & 3) * 8;
    const unsigned short* gb = BT + (size_t)(n0 + (t >> 2)) * K + (t & 3) * 8;
    const int nk = K >> 5;

#define GSTAGE(buf, kt)                                                       \
    {                                                                         \
        const int k0_ = (kt) * 32;                                            \
        GLDS16(ga + k0_, &As[buf][t * 8]);                                    \
        GLDS16(ga + (size_t)64 * K + k0_, &As[buf][t * 8 + 64 * 32]);         \
        if (t < 256) GLDS16(gb + k0_, &Bs[buf][t * 8]);                       \
    }

    GSTAGE(0, 0);
    GSTAGE(1, 1);

    int cb = 0, pfb = 2;
#pragma unroll 1
    for (int kt = 0; kt < nk; ++kt) {
        if (kt + 1 < nk) asm volatile("s_waitcnt vmcnt(3)" ::: "memory");
        else             asm volatile("s_waitcnt vmcnt(0)" ::: "memory");
        __builtin_amdgcn_s_barrier();
        __builtin_amdgcn_sched_barrier(0);
        if (kt + 2 < nk) GSTAGE(pfb, kt + 2);
        pfb = (pfb == 2) ? 0 : pfb + 1;
        const int mycb = cb;
        cb = (cb == 2) ? 0 : cb + 1;
        bf16x8 af[4], bfr[2];
#pragma unroll
        for (int m = 0; m < 4; m++)
            af[m] = *(const bf16x8*)&As[mycb][(wr * 64 + m * 16 + l15) * 32 + lhi * 8];
#pragma unroll
        for (int n = 0; n < 2; n++)
            bfr[n] = *(const bf16x8*)&Bs[mycb][(wc * 32 + n * 16 + l15) * 32 + lhi * 8];
#pragma unroll
        for (int m = 0; m < 4; m++)
#pragma unroll
            for (int n = 0; n < 2; n++)
                acc[m][n] = __builtin_amdgcn_mfma_f32_16x16x32_bf16(
                    af[m], bfr[n], acc[m][n], 0, 0, 0);
    }
#undef GSTAGE
#pragma unroll
    for (int m = 0; m < 4; m++) {
        int row = m0 + wr * 64 + m * 16 + lhi * 4;
#pragma unroll
        for (int n = 0; n < 2; n++) {
            int col = n0 + wc * 32 + n * 16 + l15;
            if (BF16OUT) {
#pragma unroll
                for (int r = 0; r < 4; r++)
                    Cb[(size_t)(row + r) * N + col] = f2bf(acc[m][n][r]);
            } else {
#pragma unroll
                for (int r = 0; r < 4; r++)
                    C0[(size_t)(row + r) * N + col] = acc[m][n][r];
            }
        }
    }
}

// -------- RoPE for Q (pre-scaled by 1/sqrt(HD)*log2e), bf16 in/out ---------
__global__ void rope_q_kernel(const unsigned short* __restrict__ Cqkv,
                              const float* __restrict__ cb,
                              const float* __restrict__ sb,
                              unsigned short* __restrict__ Q) {
    const float CS = 0.125f * 1.44269504f;
    int g = blockIdx.x * 256 + threadIdx.x;  // 2048*32*32
    int i = g & 31;
    int h = (g >> 5) & 31;
    int s = g >> 10;
    ushort2 v = *(const ushort2*)&Cqkv[(size_t)s * 3072 + h * 64 + 2 * i];
    float vx = bf2f(v.x), vy = bf2f(v.y);
    float cc = cb[s * 32 + i], ss = sb[s * 32 + i];
    ushort2 o;
    o.x = f2bf((vx * cc - vy * ss) * CS);
    o.y = f2bf((vx * ss + vy * cc) * CS);
    *(ushort2*)&Q[(size_t)h * (S_LEN * HD) + s * HD + 2 * i] = o;
}

// ---------------- RoPE for K (bf16 in/out): -> Kb bf16 [NKV][S][HD] --------
__global__ void rope_k_kernel(const unsigned short* __restrict__ Cqkv,
                              const float* __restrict__ cb,
                              const float* __restrict__ sb,
                              unsigned short* __restrict__ Kb) {
    int g = blockIdx.x * 256 + threadIdx.x;  // 2048*8*32
    int i = g & 31;
    int kvh = (g >> 5) & 7;
    int s = g >> 8;
    ushort2 v = *(const ushort2*)&Cqkv[(size_t)s * 3072 + 2048 + kvh * 64 + 2 * i];
    float vx = bf2f(v.x), vy = bf2f(v.y);
    float cc = cb[s * 32 + i], ss = sb[s * 32 + i];
    ushort2 o;
    o.x = f2bf(vx * cc - vy * ss);
    o.y = f2bf(vx * ss + vy * cc);
    *(ushort2*)&Kb[(size_t)kvh * (S_LEN * HD) + s * HD + 2 * i] = o;
}

// -------- V transpose (bf16 in/out): Cqkv -> VT bf16 [NKV][HD][S] ----------
__global__ void v_transpose_kernel(const unsigned short* __restrict__ Cqkv,
                                   unsigned short* __restrict__ VT) {
    __shared__ unsigned short tile[32][33];
    int kvh = blockIdx.z;
    int d0 = blockIdx.x * 32, s0 = blockIdx.y * 32;
    int tx = threadIdx.x, ty = threadIdx.y;
#pragma unroll
    for (int i = 0; i < 32; i += 8)
        tile[ty + i][tx] =
            Cqkv[(size_t)(s0 + ty + i) * 3072 + 2560 + kvh * 64 + d0 + tx];
    __syncthreads();
#pragma unroll
    for (int i = 0; i < 32; i += 8)
        VT[(size_t)kvh * (HD * S_LEN) + (size_t)(d0 + ty + i) * S_LEN + s0 + tx] =
            tile[tx][ty + i];
}

// ---------------- flash attention v9: uniform 8-round units, dbuf ----------
// 1280 blocks x 256 threads (4 waves), 32KB LDS -> 5 blocks/CU ALL resident
// (20 waves/CU). Unit u (0..39) of head h: 8-tile KV-chunk of strip kUQT[u].
// Strips qt>=4 write fp32 partials (nc=2..4); flash_combine merges.
__global__ __launch_bounds__(256) void flash_kernel(
    const unsigned short* __restrict__ Q, const unsigned short* __restrict__ Kg,
    const unsigned short* __restrict__ VTg, unsigned short* __restrict__ O,
    float* __restrict__ OpA, float* __restrict__ OpB, float* __restrict__ ML) {
    __shared__ unsigned short Ks[2][4096];
    __shared__ unsigned short Vs[2][4096];
    const int t = threadIdx.x, lane = t & 63, wave = t >> 6;
    const int l31 = lane & 31, hi = lane >> 5;
    const int bid = blockIdx.x;
    const int h = bid & 31, u = bid >> 5;  // u 0..39
    const int qt = kUQT[u], ch = kUCH[u];
    const int sp = (qt >= 4);
    const int kvh = h >> 2;

    const int kt0 = ch * 8;
    const int ktN = min(kt0 + 8, 2 * qt + 2);

    const int srow = t >> 3;
    const int scol = ((t & 7) * 8) ^ ((srow & 7) * 8);  // source-side swizzle
    const unsigned short* gk = Kg + ((size_t)kvh * S_LEN + srow) * HD + scol;
    const unsigned short* gv = VTg + ((size_t)kvh * HD + srow) * S_LEN + scol;

    const int q0 = qt * 128;
    const int qw0 = q0 + wave * 32;  // wave's first q row
    const int q = qw0 + l31;         // THIS lane's q row

    const unsigned short* qp = Q + ((size_t)h * S_LEN + q) * HD + hi * 8;
    bf16x8 qf0 = *(const bf16x8*)(qp);
    bf16x8 qf1 = *(const bf16x8*)(qp + 16);
    bf16x8 qf2 = *(const bf16x8*)(qp + 32);
    bf16x8 qf3 = *(const bf16x8*)(qp + 48);

    f32x16 oacc0 = {}, oacc1 = {};  // O^T: col q, rows d (0..31 / 32..63)
    float mrun = -1e30f, lrun = 0.f;

#define FSTAGE(buf, kt)                                                       \
    {                                                                         \
        const size_t kv_ = (size_t)(kt) * 64;                                 \
        GLDS16(gk + kv_ * HD, &Ks[buf][t * 8]);                               \
        GLDS16(gk + (kv_ + 32) * HD, &Ks[buf][t * 8 + 2048]);                 \
        GLDS16(gv + kv_, &Vs[buf][t * 8]);                                    \
        GLDS16(gv + (size_t)32 * S_LEN + kv_, &Vs[buf][t * 8 + 2048]);        \
    }

    FSTAGE(0, kt0);  // kt0 is even -> buffer parity kt&1 starts at 0

#pragma unroll 1
    for (int kt = kt0; kt < ktN; ++kt) {
        asm volatile("s_waitcnt vmcnt(0)" ::: "memory");
        __builtin_amdgcn_s_barrier();
        __builtin_amdgcn_sched_barrier(0);
        if (kt + 1 < ktN) FSTAGE((kt + 1) & 1, kt + 1);
        const int kv0 = kt * 64;
        if (kv0 > qw0 + 31) continue;  // fully-masked for this wave
        const unsigned short* ksb = Ks[kt & 1];
        const unsigned short* vsb = Vs[kt & 1];
        const int sw = (l31 & 7) * 8;
        // S^T = K Q^T
        f32x16 s0 = {}, s1 = {};
#pragma unroll
        for (int kc = 0; kc < 4; kc++) {
            bf16x8 k0 = *(const bf16x8*)&ksb[l31 * 64 + ((16 * kc + 8 * hi) ^ sw)];
            bf16x8 k1 = *(const bf16x8*)&ksb[(32 + l31) * 64 + ((16 * kc + 8 * hi) ^ sw)];
            bf16x8 qc = (kc == 0) ? qf0 : (kc == 1) ? qf1 : (kc == 2) ? qf2 : qf3;
            s0 = __builtin_amdgcn_mfma_f32_32x32x16_bf16(k0, qc, s0, 0, 0, 0);
            s1 = __builtin_amdgcn_mfma_f32_32x32x16_bf16(k1, qc, s1, 0, 0, 0);
        }
        float p0[16], p1[16];
        if (kv0 + 63 <= qw0) {
#pragma unroll
            for (int r = 0; r < 16; r++) { p0[r] = s0[r]; p1[r] = s1[r]; }
        } else {
#pragma unroll
            for (int r = 0; r < 16; r++) {
                int rr = (r & 3) + 8 * (r >> 2) + 4 * hi;
                p0[r] = (kv0 + rr <= q) ? s0[r] : -1e30f;
                p1[r] = (kv0 + 32 + rr <= q) ? s1[r] : -1e30f;
            }
        }
        float t8[8];
#pragma unroll
        for (int r = 0; r < 8; r++)
            t8[r] = fmaxf(fmaxf(p0[r], p0[r + 8]), fmaxf(p1[r], p1[r + 8]));
        float lm = fmaxf(fmaxf(fmaxf(t8[0], t8[4]), fmaxf(t8[1], t8[5])),
                         fmaxf(fmaxf(t8[2], t8[6]), fmaxf(t8[3], t8[7])));
        if (!__all(lm - mrun <= 8.f)) {
            float rm = fmaxf(lm, __shfl_xor(lm, 32));
            float mnew = fmaxf(mrun, rm);
            float sc = exp2f(mrun - mnew);
            mrun = mnew;
            lrun *= sc;
            oacc0 *= sc;
            oacc1 *= sc;
        }
#pragma unroll
        for (int r = 0; r < 16; r++) {
            p0[r] = exp2f(p0[r] - mrun);
            p1[r] = exp2f(p1[r] - mrun);
        }
        float sA = 0.f, sB = 0.f, sC = 0.f, sD = 0.f;
#pragma unroll
        for (int r = 0; r < 4; r++) {
            sA += p0[r] + p1[r];
            sB += p0[r + 4] + p1[r + 4];
            sC += p0[r + 8] + p1[r + 8];
            sD += p0[r + 12] + p1[r + 12];
        }
        lrun += (sA + sB) + (sC + sD);
        bf16x8 pf[4];
#pragma unroll
        for (int kc = 0; kc < 4; kc++) {
            const int sub = (kc & 1) * 8;
            uint32_t Wl0, Wl1, Wh0, Wh1;
            if (kc < 2) {
                Wl0 = cvt_pk_bf16(p0[sub + 0], p0[sub + 1]);
                Wl1 = cvt_pk_bf16(p0[sub + 2], p0[sub + 3]);
                Wh0 = cvt_pk_bf16(p0[sub + 4], p0[sub + 5]);
                Wh1 = cvt_pk_bf16(p0[sub + 6], p0[sub + 7]);
            } else {
                Wl0 = cvt_pk_bf16(p1[sub + 0], p1[sub + 1]);
                Wl1 = cvt_pk_bf16(p1[sub + 2], p1[sub + 3]);
                Wh0 = cvt_pk_bf16(p1[sub + 4], p1[sub + 5]);
                Wh1 = cvt_pk_bf16(p1[sub + 6], p1[sub + 7]);
            }
            uint32_t sw0 = hi ? Wl0 : Wh0, sw1 = hi ? Wl1 : Wh1;  // sent
            uint32_t rc0 = __shfl_xor((int)sw0, 32);
            uint32_t rc1 = __shfl_xor((int)sw1, 32);
            uint32_t kp0 = hi ? Wh0 : Wl0, kp1 = hi ? Wh1 : Wl1;  // kept
            uint32_t F0 = hi ? rc0 : kp0;
            uint32_t F1 = hi ? rc1 : kp1;
            uint32_t F2 = hi ? kp0 : rc0;
            uint32_t F3 = hi ? kp1 : rc1;
            uint4 fu = {F0, F1, F2, F3};
            pf[kc] = *(const bf16x8*)&fu;
        }
#pragma unroll
        for (int kc = 0; kc < 4; kc++) {
            bf16x8 v0 = *(const bf16x8*)&vsb[l31 * 64 + ((16 * kc + 8 * hi) ^ sw)];
            bf16x8 v1 = *(const bf16x8*)&vsb[(32 + l31) * 64 + ((16 * kc + 8 * hi) ^ sw)];
            oacc0 = __builtin_amdgcn_mfma_f32_32x32x16_bf16(v0, pf[kc], oacc0, 0, 0, 0);
            oacc1 = __builtin_amdgcn_mfma_f32_32x32x16_bf16(v1, pf[kc], oacc1, 0, 0, 0);
        }
    }
#undef FSTAGE
    lrun += __shfl_xor(lrun, 32);
    const int qrow = wave * 32 + l31;
    if (sp) {
        const int slot = h * 36 + slot_base(qt) + ch;
        float* base = (slot < 384) ? OpA + (size_t)slot * 8192
                                   : OpB + (size_t)(slot - 384) * 8192;
        float* po = base + (size_t)qrow * 64 + 4 * hi;
#pragma unroll
        for (int g = 0; g < 4; g++) {
            float4 a = {oacc0[4 * g], oacc0[4 * g + 1], oacc0[4 * g + 2], oacc0[4 * g + 3]};
            *(float4*)(po + 8 * g) = a;
            float4 b = {oacc1[4 * g], oacc1[4 * g + 1], oacc1[4 * g + 2], oacc1[4 * g + 3]};
            *(float4*)(po + 32 + 8 * g) = b;
        }
        if (hi == 0) {
            ML[((size_t)slot * 128 + qrow) * 2] = mrun;
            ML[((size_t)slot * 128 + qrow) * 2 + 1] = lrun;
        }
    } else {
        float rinv = 1.f / lrun;
        unsigned short* ob = O + ((size_t)h * S_LEN + q) * HD + 4 * hi;
#pragma unroll
        for (int g = 0; g < 4; g++) {
            uint32_t a0 = cvt_pk_bf16(oacc0[4 * g] * rinv, oacc0[4 * g + 1] * rinv);
            uint32_t a1 = cvt_pk_bf16(oacc0[4 * g + 2] * rinv, oacc0[4 * g + 3] * rinv);
            uint2 u0 = {a0, a1};
            *(uint2*)(ob + 8 * g) = u0;
            uint32_t b0 = cvt_pk_bf16(oacc1[4 * g] * rinv, oacc1[4 * g + 1] * rinv);
            uint32_t b1 = cvt_pk_bf16(oacc1[4 * g + 2] * rinv, oacc1[4 * g + 3] * rinv);
            uint2 u1 = {b0, b1};
            *(uint2*)(ob + 32 + 8 * g) = u1;
        }
    }
}

// ---------------- combine nc kv-chunk partials -> bf16 attn ----------------
__global__ __launch_bounds__(256) void flash_combine_kernel(
    const float* __restrict__ OpA, const float* __restrict__ OpB,
    const float* __restrict__ ML, unsigned short* __restrict__ attn) {
    const int bid = blockIdx.x;          // 384 = 32 heads x 12 split strips
    const int h = bid & 31, j = bid >> 5;
    const int qt = 4 + j;
    const int nc = (qt < 8) ? 2 : (qt < 12) ? 3 : 4;
    const int slot0 = h * 36 + slot_base(qt);
    const int t = threadIdx.x;
    const int qrow = t >> 1, d0 = (t & 1) * 32;
    auto slotp = [&](int c) {
        int s = slot0 + c;
        return (s < 384) ? OpA + (size_t)s * 8192 : OpB + (size_t)(s - 384) * 8192;
    };
    auto mlat = [&](int c, int i) {
        return ML[((size_t)(slot0 + c) * 128 + qrow) * 2 + i];
    };
    float mA = mlat(0, 0), lA = mlat(0, 1);
    float mB = mlat(1, 0), lB = mlat(1, 1);
    float mC = -1e30f, lC = 0.f, mD = -1e30f, lD = 0.f;
    if (nc > 2) { mC = mlat(2, 0); lC = mlat(2, 1); }
    if (nc > 3) { mD = mlat(3, 0); lD = mlat(3, 1); }
    float m = fmaxf(fmaxf(mA, mB), fmaxf(mC, mD));
    float wA = exp2f(mA - m), wB = exp2f(mB - m);
    float wC = exp2f(mC - m), wD = exp2f(mD - m);
    float rinv = 1.f / (lA * wA + lB * wB + lC * wC + lD * wD);
    const float* pA = slotp(0) + (size_t)qrow * 64 + d0;
    const float* pB = slotp(1) + (size_t)qrow * 64 + d0;
    const float* pC = (nc > 2) ? slotp(2) + (size_t)qrow * 64 + d0 : pA;
    const float* pD = (nc > 3) ? slotp(3) + (size_t)qrow * 64 + d0 : pA;
    unsigned short* po = attn + ((size_t)h * S_LEN + qt * 128 + qrow) * HD + d0;
#pragma unroll
    for (int dd = 0; dd < 32; dd += 4) {
        float4 a = *(const float4*)&pA[dd];
        float4 b = *(const float4*)&pB[dd];
        float4 acc = {a.x * wA + b.x * wB, a.y * wA + b.y * wB,
                      a.z * wA + b.z * wB, a.w * wA + b.w * wB};
        if (nc > 2) {
            float4 c = *(const float4*)&pC[dd];
            acc.x += c.x * wC; acc.y += c.y * wC;
            acc.z += c.z * wC; acc.w += c.w * wC;
        }
        if (nc > 3) {
            float4 d = *(const float4*)&pD[dd];
            acc.x += d.x * wD; acc.y += d.y * wD;
            acc.z += d.z * wD; acc.w += d.w * wD;
        }
        ushort4 o;
        o.x = f2bf(acc.x * rinv);
        o.y = f2bf(acc.y * rinv);
        o.z = f2bf(acc.z * rinv);
        o.w = f2bf(acc.w * rinv);
        *(ushort4*)&po[dd] = o;
    }
}

// ---------------- per-head fw GEMM + SiLU -> h2 bf16 [S][DMODEL] -----------
__global__ __launch_bounds__(256) void fw_silu_kernel(
    const unsigned short* __restrict__ AT, const unsigned short* __restrict__ fwT,
    const float* __restrict__ fb, unsigned short* __restrict__ h2) {
    const int t = threadIdx.x, lane = t & 63, wave = t >> 6;
    const int l15 = lane & 15, lhi = lane >> 4;
    const int r0 = blockIdx.x * 64 + wave * 16;
    const unsigned short* ap = AT + (size_t)(r0 + l15) * HD + lhi * 8;
    bf16x8 a0 = *(const bf16x8*)ap;
    bf16x8 a1 = *(const bf16x8*)(ap + 32);
    f32x4 acc[4] = {};
#pragma unroll
    for (int nb = 0; nb < 4; nb++) {
        const unsigned short* bp = fwT + (size_t)(nb * 16 + l15) * HD + lhi * 8;
        bf16x8 b0 = *(const bf16x8*)bp;
        bf16x8 b1 = *(const bf16x8*)(bp + 32);
        acc[nb] = __builtin_amdgcn_mfma_f32_16x16x32_bf16(a0, b0, acc[nb], 0, 0, 0);
        acc[nb] = __builtin_amdgcn_mfma_f32_16x16x32_bf16(a1, b1, acc[nb], 0, 0, 0);
    }
#pragma unroll
    for (int nb = 0; nb < 4; nb++) {
        int col = nb * 16 + l15;
        float bias = fb[col];
#pragma unroll
        for (int r = 0; r < 4; r++) {
            int row = r0 + lhi * 4 + r;  // h*S + s
            int s = row & (S_LEN - 1), hh = row >> 11;
            float x = acc[nb][r] + bias;
            float sg = 1.f / (1.f + exp2f(-x * 1.44269504f));
            h2[(size_t)s * DMODEL + hh * HD + col] = f2bf(x * sg);
        }
    }
}

extern "C" void kernel_launch(void* const* d_in, const int* in_sizes, int n_in,
                              void* d_out, int out_size, void* d_ws, size_t ws_size,
                              hipStream_t stream) {
    const float* x = (const float*)d_in[0];
    const float* fcos = (const float*)d_in[1];
    const float* fsin = (const float*)d_in[2];
    const float* wq = (const float*)d_in[4];
    const float* wk = (const float*)d_in[5];
    const float* wv = (const float*)d_in[6];
    const float* wo = (const float*)d_in[7];
    const float* fw = (const float*)d_in[8];
    const float* fb = (const float*)d_in[9];
    float* out = (float*)d_out;

    char* ws = (char*)d_ws;
    size_t off = 0;
    auto alloc = [&](size_t bytes) {
        void* p = ws + off;
        off += (bytes + 255) & ~(size_t)255;
        return p;
    };
    unsigned short* wqkvT = (unsigned short*)alloc((size_t)3072 * 2048 * 2);
    unsigned short* woT   = (unsigned short*)alloc((size_t)2048 * 2048 * 2);
    unsigned short* fwT   = (unsigned short*)alloc((size_t)64 * 64 * 2);
    unsigned short* Cqkv  = (unsigned short*)alloc((size_t)2048 * 3072 * 2);
    unsigned short* Qb    = (unsigned short*)alloc((size_t)NH * S_LEN * HD * 2);
    unsigned short* Kb    = (unsigned short*)alloc((size_t)NKV * S_LEN * HD * 2);
    unsigned short* VT    = (unsigned short*)alloc((size_t)NKV * HD * S_LEN * 2);
    unsigned short* xb    = (unsigned short*)alloc((size_t)2048 * 2048 * 2);
    float*          ML    = (float*)alloc((size_t)1152 * 128 * 2 * 4);
    unsigned short* attn  = (unsigned short*)alloc((size_t)NH * S_LEN * HD * 2);
    float*          OpB   = (float*)alloc((size_t)768 * 8192 * 4);  // slots 384+
    // OpA: first 384 partial slots overlay Cqkv (dead after rope/v_transpose;
    // 384 * 32KB = 12.58MB = exactly the Cqkv region)
    float* OpA = (float*)Cqkv;
    unsigned short* h2 = xb;  // reuses xb (x dead after QKV gemm)

    dim3 tb(32, 8);
    cast_bf16_kernel<<<2048, 256, 0, stream>>>(x, xb, 2048 * 2048);
    transpose_cast_kernel<<<dim3(64, 64), tb, 0, stream>>>(wq, wqkvT, 2048, 2048);
    transpose_cast_kernel<<<dim3(16, 64), tb, 0, stream>>>(wk, wqkvT + (size_t)2048 * 2048, 2048, 512);
    transpose_cast_kernel<<<dim3(16, 64), tb, 0, stream>>>(wv, wqkvT + (size_t)2560 * 2048, 2048, 512);
    transpose_cast_kernel<<<dim3(64, 64), tb, 0, stream>>>(wo, woT, 2048, 2048);
    transpose_cast_kernel<<<dim3(2, 2), tb, 0, stream>>>(fw, fwT, 64, 64);

    // QKV GEMM: 128x64 tiles -> 768 blocks (3/CU uniform), bf16 out
    gemm_bt_kernel<true><<<dim3(16, 48), 256, 0, stream>>>(
        xb, wqkvT, nullptr, Cqkv, 2048, 3072, 2048);

    rope_q_kernel<<<8192, 256, 0, stream>>>(Cqkv, fcos, fsin, Qb);
    rope_k_kernel<<<2048, 256, 0, stream>>>(Cqkv, fcos, fsin, Kb);
    v_transpose_kernel<<<dim3(2, 64, 8), tb, 0, stream>>>(Cqkv, VT);

    flash_kernel<<<1280, 256, 0, stream>>>(Qb, Kb, VT, attn, OpA, OpB, ML);
    flash_combine_kernel<<<384, 256, 0, stream>>>(OpA, OpB, ML, attn);

    fw_silu_kernel<<<1024, 256, 0, stream>>>(attn, fwT, fb, h2);

    // wo GEMM: 128x64 tiles -> 512 blocks (2/CU uniform), fp32 out, full K
    gemm_bt_kernel<false><<<dim3(16, 32), 256, 0, stream>>>(
        h2, woT, out, nullptr, 2048, 2048, 2048);
}

// Round 14
// 169.691 us; speedup vs baseline: 1.1499x; 1.1499x over previous
//
#include <hip/hip_runtime.h>
#include <stdint.h>

#define S_LEN 2048
#define DMODEL 2048
#define NH 32
#define NKV 8
#define HD 64

typedef __attribute__((ext_vector_type(8))) __bf16 bf16x8;
typedef __attribute__((ext_vector_type(4))) float f32x4;
typedef __attribute__((ext_vector_type(16))) float f32x16;

__device__ __forceinline__ unsigned short f2bf(float f) {
    union { float f; uint32_t u; } v; v.f = f;
    uint32_t u = v.u;
    u += 0x7FFFu + ((u >> 16) & 1u);
    return (unsigned short)(u >> 16);
}

__device__ __forceinline__ uint32_t cvt_pk_bf16(float lo, float hi) {
    uint32_t r;
    asm("v_cvt_pk_bf16_f32 %0, %1, %2" : "=v"(r) : "v"(lo), "v"(hi));
    return r;
}

#define GLDS16(g, l)                                                          \
    __builtin_amdgcn_global_load_lds(                                         \
        (const __attribute__((address_space(1))) unsigned int*)(g),           \
        (__attribute__((address_space(3))) unsigned int*)(l), 16, 0, 0)

// unit tables (R12): 24 units/head, sorted descending by length.
__device__ const int kUQT[24] = {15,15,7,14,14,13,13,6,12,12,11,11,5,10,10,9,9,4,8,8,3,2,1,0};
__device__ const int kUCH[24] = {0,1,0,0,1,0,1,0,0,1,0,1,0,0,1,0,1,0,0,1,0,0,0,0};
__device__ const int kUSP[24] = {1,1,0,1,1,1,1,0,1,1,1,1,0,1,1,1,1,0,1,1,0,0,0,0};

// ---------------- elementwise cast fp32 -> bf16 ----------------
__global__ void cast_bf16_kernel(const float* __restrict__ src,
                                 unsigned short* __restrict__ dst, int n) {
    int g = (blockIdx.x * blockDim.x + threadIdx.x) * 8;
    if (g >= n) return;
    float4 a = *(const float4*)&src[g];
    float4 b = *(const float4*)&src[g + 4];
    unsigned short o[8];
    o[0] = f2bf(a.x); o[1] = f2bf(a.y); o[2] = f2bf(a.z); o[3] = f2bf(a.w);
    o[4] = f2bf(b.x); o[5] = f2bf(b.y); o[6] = f2bf(b.z); o[7] = f2bf(b.w);
    *(uint4*)&dst[g] = *(const uint4*)o;
}

// ------- merged weight transposes: z selects {wq,wk,wv,wo,fw} -------------
__global__ void prep_transpose_kernel(
    const float* __restrict__ wq, const float* __restrict__ wk,
    const float* __restrict__ wv, const float* __restrict__ wo,
    const float* __restrict__ fw, unsigned short* __restrict__ wqkvT,
    unsigned short* __restrict__ woT, unsigned short* __restrict__ fwT) {
    __shared__ float tile[32][33];
    const int z = blockIdx.z;
    const float* src;
    unsigned short* dst;
    int R, C;
    if (z == 0)      { src = wq; dst = wqkvT;                         R = 2048; C = 2048; }
    else if (z == 1) { src = wk; dst = wqkvT + (size_t)2048 * 2048;   R = 2048; C = 512;  if (blockIdx.x >= 16) return; }
    else if (z == 2) { src = wv; dst = wqkvT + (size_t)2560 * 2048;   R = 2048; C = 512;  if (blockIdx.x >= 16) return; }
    else if (z == 3) { src = wo; dst = woT;                           R = 2048; C = 2048; }
    else             { src = fw; dst = fwT;                           R = 64;   C = 64;   if (blockIdx.x >= 2 || blockIdx.y >= 2) return; }
    int c0 = blockIdx.x * 32, r0 = blockIdx.y * 32;
    int tx = threadIdx.x, ty = threadIdx.y;
#pragma unroll
    for (int i = 0; i < 32; i += 8)
        tile[ty + i][tx] = src[(size_t)(r0 + ty + i) * C + c0 + tx];
    __syncthreads();
#pragma unroll
    for (int i = 0; i < 32; i += 8)
        dst[(size_t)(c0 + ty + i) * R + r0 + tx] = f2bf(tile[tx][ty + i]);
}

// ---- 128x64-tile triple-buffered counted-vmcnt bf16 GEMM (T3/T4 + T1) -----
// MODE 0: fp32 out (wo).  MODE 1: fused QKV epilogue -> Qb/Kb/VT.
template <int MODE>
__global__ __launch_bounds__(256) void gemm_bt_kernel(
    const unsigned short* __restrict__ A, const unsigned short* __restrict__ BT,
    float* __restrict__ C0, unsigned short* __restrict__ Qb,
    unsigned short* __restrict__ Kb, unsigned short* __restrict__ VT,
    const float* __restrict__ fcos, const float* __restrict__ fsin,
    int M, int N, int K) {
    __shared__ unsigned short As[3][128 * 32];
    __shared__ unsigned short Bs[3][64 * 32];
    const int t = threadIdx.x;
    const int lane = t & 63, wave = t >> 6;
    const int wr = wave >> 1, wc = wave & 1;
    const int gx = gridDim.x;
    const int nwg = gx * gridDim.y;
    const int wg = blockIdx.y * gx + blockIdx.x;
    const int swz = (wg & 7) * (nwg >> 3) + (wg >> 3);
    const int m0 = (swz % gx) * 128, n0 = (swz / gx) * 64;
    const int l15 = lane & 15, lhi = lane >> 4;
    f32x4 acc[4][2] = {};
    const unsigned short* ga = A + (size_t)(m0 + (t >> 2)) * K + (t & 3) * 8;
    const unsigned short* gb = BT + (size_t)(n0 + (t >> 2)) * K + (t & 3) * 8;
    const int nk = K >> 5;

#define GSTAGE(buf, kt)                                                       \
    {                                                                         \
        const int k0_ = (kt) * 32;                                            \
        GLDS16(ga + k0_, &As[buf][t * 8]);                                    \
        GLDS16(ga + (size_t)64 * K + k0_, &As[buf][t * 8 + 64 * 32]);         \
        if (t < 256) GLDS16(gb + k0_, &Bs[buf][t * 8]);                       \
    }

    GSTAGE(0, 0);
    GSTAGE(1, 1);

    int cb = 0, pfb = 2;
#pragma unroll 1
    for (int kt = 0; kt < nk; ++kt) {
        if (kt + 1 < nk) asm volatile("s_waitcnt vmcnt(3)" ::: "memory");
        else             asm volatile("s_waitcnt vmcnt(0)" ::: "memory");
        __builtin_amdgcn_s_barrier();
        __builtin_amdgcn_sched_barrier(0);
        if (kt + 2 < nk) GSTAGE(pfb, kt + 2);
        pfb = (pfb == 2) ? 0 : pfb + 1;
        const int mycb = cb;
        cb = (cb == 2) ? 0 : cb + 1;
        bf16x8 af[4], bfr[2];
#pragma unroll
        for (int m = 0; m < 4; m++)
            af[m] = *(const bf16x8*)&As[mycb][(wr * 64 + m * 16 + l15) * 32 + lhi * 8];
#pragma unroll
        for (int n = 0; n < 2; n++)
            bfr[n] = *(const bf16x8*)&Bs[mycb][(wc * 32 + n * 16 + l15) * 32 + lhi * 8];
#pragma unroll
        for (int m = 0; m < 4; m++)
#pragma unroll
            for (int n = 0; n < 2; n++)
                acc[m][n] = __builtin_amdgcn_mfma_f32_16x16x32_bf16(
                    af[m], bfr[n], acc[m][n], 0, 0, 0);
    }
#undef GSTAGE
    if (MODE == 0) {
#pragma unroll
        for (int m = 0; m < 4; m++) {
            int row = m0 + wr * 64 + m * 16 + lhi * 4;
#pragma unroll
            for (int n = 0; n < 2; n++) {
                int col = n0 + wc * 32 + n * 16 + l15;
#pragma unroll
                for (int r = 0; r < 4; r++)
                    C0[(size_t)(row + r) * N + col] = acc[m][n][r];
            }
        }
    } else {
        const int nblk = n0 >> 6;  // 0..47: Q heads 0..31, K 32..39, V 40..47
        if (nblk < 40) {
            // RoPE path (Q or K). pairs (2i,2i+1) on adjacent l15 lanes.
            const float CS = 0.125f * 1.44269504f;
            const bool isQ = (nblk < 32);
            unsigned short* dst = isQ ? Qb + (size_t)nblk * (S_LEN * HD)
                                      : Kb + (size_t)(nblk - 32) * (S_LEN * HD);
#pragma unroll
            for (int m = 0; m < 4; m++) {
#pragma unroll
                for (int n = 0; n < 2; n++) {
                    int col = wc * 32 + n * 16 + l15;  // head-local d
                    int i = col >> 1;
                    float sgn = (col & 1) ? 1.f : -1.f;
#pragma unroll
                    for (int r = 0; r < 4; r++) {
                        int s = m0 + wr * 64 + m * 16 + lhi * 4 + r;
                        float c = fcos[s * 32 + i], sn = fsin[s * 32 + i];
                        float v = acc[m][n][r];
                        float pv = __shfl_xor(v, 1);
                        float o = fmaf(pv, sgn * sn, v * c);
                        if (isQ) o *= CS;
                        dst[(size_t)s * HD + col] = f2bf(o);
                    }
                }
            }
        } else {
            // V path: LDS transpose [64 d][128 s] (pad 130), coalesced out
            const int kvh = nblk - 40;
            unsigned short* ldsT = (unsigned short*)As;  // 64*130*2 = 16.6KB
            __syncthreads();  // all waves done reading As/Bs
#pragma unroll
            for (int m = 0; m < 4; m++)
#pragma unroll
                for (int n = 0; n < 2; n++) {
                    int d = wc * 32 + n * 16 + l15;
#pragma unroll
                    for (int r = 0; r < 4; r++) {
                        int sl = wr * 64 + m * 16 + lhi * 4 + r;
                        ldsT[d * 130 + sl] = f2bf(acc[m][n][r]);
                    }
                }
            __syncthreads();
            const int d = t >> 2, sc = (t & 3) * 32;
            unsigned short* dst = VT + ((size_t)kvh * HD + d) * S_LEN + m0 + sc;
            const unsigned short* srcl = &ldsT[d * 130 + sc];
#pragma unroll
            for (int j = 0; j < 16; j++)
                ((uint32_t*)dst)[j] = *(const uint32_t*)&srcl[2 * j];
        }
    }
}

// ---------------- flash attention v8 (R12 version) -------------------------
__global__ __launch_bounds__(256) void flash_kernel(
    const unsigned short* __restrict__ Q, const unsigned short* __restrict__ Kg,
    const unsigned short* __restrict__ VTg, unsigned short* __restrict__ O,
    float* __restrict__ Opart, float* __restrict__ ML) {
    __shared__ unsigned short Ks[3][4096];
    __shared__ unsigned short Vs[3][4096];
    const int t = threadIdx.x, lane = t & 63, wave = t >> 6;
    const int l31 = lane & 31, hi = lane >> 5;
    const int bid = blockIdx.x;
    const int h = bid & 31, u = bid >> 5;  // u 0..23
    const int qt = kUQT[u], ch = kUCH[u], sp = kUSP[u];
    const int kvh = h >> 2;

    const int kt0 = sp ? ch * (qt + 1) : 0;
    const int ktN = sp ? kt0 + qt + 1 : 2 * qt + 2;

    const int srow = t >> 3;
    const int scol = ((t & 7) * 8) ^ ((srow & 7) * 8);  // source-side swizzle
    const unsigned short* gk = Kg + ((size_t)kvh * S_LEN + srow) * HD + scol;
    const unsigned short* gv = VTg + ((size_t)kvh * HD + srow) * S_LEN + scol;

    const int q0 = qt * 128;
    const int qw0 = q0 + wave * 32;  // wave's first q row
    const int q = qw0 + l31;         // THIS lane's q row

    const unsigned short* qp = Q + ((size_t)h * S_LEN + q) * HD + hi * 8;
    bf16x8 qf0 = *(const bf16x8*)(qp);
    bf16x8 qf1 = *(const bf16x8*)(qp + 16);
    bf16x8 qf2 = *(const bf16x8*)(qp + 32);
    bf16x8 qf3 = *(const bf16x8*)(qp + 48);

    f32x16 oacc0 = {}, oacc1 = {};  // O^T: col q, rows d (0..31 / 32..63)
    float mrun = -1e30f, lrun = 0.f;

    {
        const size_t kva = (size_t)kt0 * 64, kvb = kva + 64;
        GLDS16(gk + kva * HD, &Ks[0][t * 8]);
        GLDS16(gk + (kva + 32) * HD, &Ks[0][t * 8 + 2048]);
        GLDS16(gv + kva, &Vs[0][t * 8]);
        GLDS16(gv + (size_t)32 * S_LEN + kva, &Vs[0][t * 8 + 2048]);
        GLDS16(gk + kvb * HD, &Ks[1][t * 8]);
        GLDS16(gk + (kvb + 32) * HD, &Ks[1][t * 8 + 2048]);
        GLDS16(gv + kvb, &Vs[1][t * 8]);
        GLDS16(gv + (size_t)32 * S_LEN + kvb, &Vs[1][t * 8 + 2048]);
    }

    int cb = 0, pfb = 2;
#pragma unroll 1
    for (int kt = kt0; kt < ktN; ++kt) {
        if (kt + 1 < ktN) asm volatile("s_waitcnt vmcnt(4)" ::: "memory");
        else              asm volatile("s_waitcnt vmcnt(0)" ::: "memory");
        __builtin_amdgcn_s_barrier();
        __builtin_amdgcn_sched_barrier(0);
        if (kt + 2 < ktN) {
            const size_t kvp = (size_t)(kt + 2) * 64;
            GLDS16(gk + kvp * HD, &Ks[pfb][t * 8]);
            GLDS16(gk + (kvp + 32) * HD, &Ks[pfb][t * 8 + 2048]);
            GLDS16(gv + kvp, &Vs[pfb][t * 8]);
            GLDS16(gv + (size_t)32 * S_LEN + kvp, &Vs[pfb][t * 8 + 2048]);
        }
        pfb = (pfb == 2) ? 0 : pfb + 1;
        const int kv0 = kt * 64;
        const int mycb = cb;
        cb = (cb == 2) ? 0 : cb + 1;
        if (kv0 > qw0 + 31) continue;  // fully-masked for this wave
        const unsigned short* ksb = Ks[mycb];
        const unsigned short* vsb = Vs[mycb];
        const int sw = (l31 & 7) * 8;
        // S^T = K Q^T
        f32x16 s0 = {}, s1 = {};
#pragma unroll
        for (int kc = 0; kc < 4; kc++) {
            bf16x8 k0 = *(const bf16x8*)&ksb[l31 * 64 + ((16 * kc + 8 * hi) ^ sw)];
            bf16x8 k1 = *(const bf16x8*)&ksb[(32 + l31) * 64 + ((16 * kc + 8 * hi) ^ sw)];
            bf16x8 qc = (kc == 0) ? qf0 : (kc == 1) ? qf1 : (kc == 2) ? qf2 : qf3;
            s0 = __builtin_amdgcn_mfma_f32_32x32x16_bf16(k0, qc, s0, 0, 0, 0);
            s1 = __builtin_amdgcn_mfma_f32_32x32x16_bf16(k1, qc, s1, 0, 0, 0);
        }
        float p0[16], p1[16];
        if (kv0 + 63 <= qw0) {
#pragma unroll
            for (int r = 0; r < 16; r++) { p0[r] = s0[r]; p1[r] = s1[r]; }
        } else {
#pragma unroll
            for (int r = 0; r < 16; r++) {
                int rr = (r & 3) + 8 * (r >> 2) + 4 * hi;
                p0[r] = (kv0 + rr <= q) ? s0[r] : -1e30f;
                p1[r] = (kv0 + 32 + rr <= q) ? s1[r] : -1e30f;
            }
        }
        float t8[8];
#pragma unroll
        for (int r = 0; r < 8; r++)
            t8[r] = fmaxf(fmaxf(p0[r], p0[r + 8]), fmaxf(p1[r], p1[r + 8]));
        float lm = fmaxf(fmaxf(fmaxf(t8[0], t8[4]), fmaxf(t8[1], t8[5])),
                         fmaxf(fmaxf(t8[2], t8[6]), fmaxf(t8[3], t8[7])));
        if (!__all(lm - mrun <= 8.f)) {
            float rm = fmaxf(lm, __shfl_xor(lm, 32));
            float mnew = fmaxf(mrun, rm);
            float sc = exp2f(mrun - mnew);
            mrun = mnew;
            lrun *= sc;
            oacc0 *= sc;
            oacc1 *= sc;
        }
#pragma unroll
        for (int r = 0; r < 16; r++) {
            p0[r] = exp2f(p0[r] - mrun);
            p1[r] = exp2f(p1[r] - mrun);
        }
        float sA = 0.f, sB = 0.f, sC = 0.f, sD = 0.f;
#pragma unroll
        for (int r = 0; r < 4; r++) {
            sA += p0[r] + p1[r];
            sB += p0[r + 4] + p1[r + 4];
            sC += p0[r + 8] + p1[r + 8];
            sD += p0[r + 12] + p1[r + 12];
        }
        lrun += (sA + sB) + (sC + sD);
        bf16x8 pf[4];
#pragma unroll
        for (int kc = 0; kc < 4; kc++) {
            const int sub = (kc & 1) * 8;
            uint32_t Wl0, Wl1, Wh0, Wh1;
            if (kc < 2) {
                Wl0 = cvt_pk_bf16(p0[sub + 0], p0[sub + 1]);
                Wl1 = cvt_pk_bf16(p0[sub + 2], p0[sub + 3]);
                Wh0 = cvt_pk_bf16(p0[sub + 4], p0[sub + 5]);
                Wh1 = cvt_pk_bf16(p0[sub + 6], p0[sub + 7]);
            } else {
                Wl0 = cvt_pk_bf16(p1[sub + 0], p1[sub + 1]);
                Wl1 = cvt_pk_bf16(p1[sub + 2], p1[sub + 3]);
                Wh0 = cvt_pk_bf16(p1[sub + 4], p1[sub + 5]);
                Wh1 = cvt_pk_bf16(p1[sub + 6], p1[sub + 7]);
            }
            uint32_t sw0 = hi ? Wl0 : Wh0, sw1 = hi ? Wl1 : Wh1;  // sent
            uint32_t rc0 = __shfl_xor((int)sw0, 32);
            uint32_t rc1 = __shfl_xor((int)sw1, 32);
            uint32_t kp0 = hi ? Wh0 : Wl0, kp1 = hi ? Wh1 : Wl1;  // kept
            uint32_t F0 = hi ? rc0 : kp0;
            uint32_t F1 = hi ? rc1 : kp1;
            uint32_t F2 = hi ? kp0 : rc0;
            uint32_t F3 = hi ? kp1 : rc1;
            uint4 fu = {F0, F1, F2, F3};
            pf[kc] = *(const bf16x8*)&fu;
        }
#pragma unroll
        for (int kc = 0; kc < 4; kc++) {
            bf16x8 v0 = *(const bf16x8*)&vsb[l31 * 64 + ((16 * kc + 8 * hi) ^ sw)];
            bf16x8 v1 = *(const bf16x8*)&vsb[(32 + l31) * 64 + ((16 * kc + 8 * hi) ^ sw)];
            oacc0 = __builtin_amdgcn_mfma_f32_32x32x16_bf16(v0, pf[kc], oacc0, 0, 0, 0);
            oacc1 = __builtin_amdgcn_mfma_f32_32x32x16_bf16(v1, pf[kc], oacc1, 0, 0, 0);
        }
    }
    lrun += __shfl_xor(lrun, 32);
    const int qrow = wave * 32 + l31;
    if (sp) {
        const int pidx = (h * 8 + (qt - 8)) * 2 + ch;
        float* po = Opart + ((size_t)pidx * 128 + qrow) * 64 + 4 * hi;
#pragma unroll
        for (int g = 0; g < 4; g++) {
            float4 a = {oacc0[4 * g], oacc0[4 * g + 1], oacc0[4 * g + 2], oacc0[4 * g + 3]};
            *(float4*)(po + 8 * g) = a;
            float4 b = {oacc1[4 * g], oacc1[4 * g + 1], oacc1[4 * g + 2], oacc1[4 * g + 3]};
            *(float4*)(po + 32 + 8 * g) = b;
        }
        if (hi == 0) {
            ML[((size_t)pidx * 128 + qrow) * 2] = mrun;
            ML[((size_t)pidx * 128 + qrow) * 2 + 1] = lrun;
        }
    } else {
        float rinv = 1.f / lrun;
        unsigned short* ob = O + ((size_t)h * S_LEN + q) * HD + 4 * hi;
#pragma unroll
        for (int g = 0; g < 4; g++) {
            uint32_t a0 = cvt_pk_bf16(oacc0[4 * g] * rinv, oacc0[4 * g + 1] * rinv);
            uint32_t a1 = cvt_pk_bf16(oacc0[4 * g + 2] * rinv, oacc0[4 * g + 3] * rinv);
            uint2 u0 = {a0, a1};
            *(uint2*)(ob + 8 * g) = u0;
            uint32_t b0 = cvt_pk_bf16(oacc1[4 * g] * rinv, oacc1[4 * g + 1] * rinv);
            uint32_t b1 = cvt_pk_bf16(oacc1[4 * g + 2] * rinv, oacc1[4 * g + 3] * rinv);
            uint2 u1 = {b0, b1};
            *(uint2*)(ob + 32 + 8 * g) = u1;
        }
    }
}

// ---------------- combine two kv-chunk partials -> bf16 attn ---------------
__global__ __launch_bounds__(256) void flash_combine_kernel(
    const float* __restrict__ Opart, const float* __restrict__ ML,
    unsigned short* __restrict__ attn) {
    const int bid = blockIdx.x;          // 256 = 32 heads x 8 split strips
    const int h = bid & 31, j = bid >> 5;
    const int qt = 8 + j;
    const int t = threadIdx.x;
    const int qrow = t >> 1, d0 = (t & 1) * 32;
    const int base = (h * 8 + j) * 2;
    const float mA = ML[((size_t)base * 128 + qrow) * 2];
    const float lA = ML[((size_t)base * 128 + qrow) * 2 + 1];
    const float mB = ML[((size_t)(base + 1) * 128 + qrow) * 2];
    const float lB = ML[((size_t)(base + 1) * 128 + qrow) * 2 + 1];
    const float m = fmaxf(mA, mB);
    const float wA = exp2f(mA - m), wB = exp2f(mB - m);
    const float rinv = 1.f / (lA * wA + lB * wB);
    const float* pA = Opart + ((size_t)base * 128 + qrow) * 64 + d0;
    const float* pB = Opart + ((size_t)(base + 1) * 128 + qrow) * 64 + d0;
    unsigned short* po = attn + ((size_t)h * S_LEN + qt * 128 + qrow) * HD + d0;
#pragma unroll
    for (int dd = 0; dd < 32; dd += 8) {
        float4 a0 = *(const float4*)&pA[dd], a1 = *(const float4*)&pA[dd + 4];
        float4 b0 = *(const float4*)&pB[dd], b1 = *(const float4*)&pB[dd + 4];
        unsigned short o[8];
        o[0] = f2bf((a0.x * wA + b0.x * wB) * rinv);
        o[1] = f2bf((a0.y * wA + b0.y * wB) * rinv);
        o[2] = f2bf((a0.z * wA + b0.z * wB) * rinv);
        o[3] = f2bf((a0.w * wA + b0.w * wB) * rinv);
        o[4] = f2bf((a1.x * wA + b1.x * wB) * rinv);
        o[5] = f2bf((a1.y * wA + b1.y * wB) * rinv);
        o[6] = f2bf((a1.z * wA + b1.z * wB) * rinv);
        o[7] = f2bf((a1.w * wA + b1.w * wB) * rinv);
        *(uint4*)&po[dd] = *(const uint4*)o;
    }
}

// ---------------- per-head fw GEMM + SiLU -> h2 bf16 [S][DMODEL] -----------
__global__ __launch_bounds__(256) void fw_silu_kernel(
    const unsigned short* __restrict__ AT, const unsigned short* __restrict__ fwT,
    const float* __restrict__ fb, unsigned short* __restrict__ h2) {
    const int t = threadIdx.x, lane = t & 63, wave = t >> 6;
    const int l15 = lane & 15, lhi = lane >> 4;
    const int r0 = blockIdx.x * 64 + wave * 16;
    const unsigned short* ap = AT + (size_t)(r0 + l15) * HD + lhi * 8;
    bf16x8 a0 = *(const bf16x8*)ap;
    bf16x8 a1 = *(const bf16x8*)(ap + 32);
    f32x4 acc[4] = {};
#pragma unroll
    for (int nb = 0; nb < 4; nb++) {
        const unsigned short* bp = fwT + (size_t)(nb * 16 + l15) * HD + lhi * 8;
        bf16x8 b0 = *(const bf16x8*)bp;
        bf16x8 b1 = *(const bf16x8*)(bp + 32);
        acc[nb] = __builtin_amdgcn_mfma_f32_16x16x32_bf16(a0, b0, acc[nb], 0, 0, 0);
        acc[nb] = __builtin_amdgcn_mfma_f32_16x16x32_bf16(a1, b1, acc[nb], 0, 0, 0);
    }
#pragma unroll
    for (int nb = 0; nb < 4; nb++) {
        int col = nb * 16 + l15;
        float bias = fb[col];
#pragma unroll
        for (int r = 0; r < 4; r++) {
            int row = r0 + lhi * 4 + r;  // h*S + s
            int s = row & (S_LEN - 1), hh = row >> 11;
            float x = acc[nb][r] + bias;
            float sg = 1.f / (1.f + exp2f(-x * 1.44269504f));
            h2[(size_t)s * DMODEL + hh * HD + col] = f2bf(x * sg);
        }
    }
}

extern "C" void kernel_launch(void* const* d_in, const int* in_sizes, int n_in,
                              void* d_out, int out_size, void* d_ws, size_t ws_size,
                              hipStream_t stream) {
    const float* x = (const float*)d_in[0];
    const float* fcos = (const float*)d_in[1];
    const float* fsin = (const float*)d_in[2];
    const float* wq = (const float*)d_in[4];
    const float* wk = (const float*)d_in[5];
    const float* wv = (const float*)d_in[6];
    const float* wo = (const float*)d_in[7];
    const float* fw = (const float*)d_in[8];
    const float* fb = (const float*)d_in[9];
    float* out = (float*)d_out;

    char* ws = (char*)d_ws;
    size_t off = 0;
    auto alloc = [&](size_t bytes) {
        void* p = ws + off;
        off += (bytes + 255) & ~(size_t)255;
        return p;
    };
    unsigned short* wqkvT = (unsigned short*)alloc((size_t)3072 * 2048 * 2);
    unsigned short* woT   = (unsigned short*)alloc((size_t)2048 * 2048 * 2);
    unsigned short* fwT   = (unsigned short*)alloc((size_t)64 * 64 * 2);
    unsigned short* Qb    = (unsigned short*)alloc((size_t)NH * S_LEN * HD * 2);
    unsigned short* Kb    = (unsigned short*)alloc((size_t)NKV * S_LEN * HD * 2);
    unsigned short* VT    = (unsigned short*)alloc((size_t)NKV * HD * S_LEN * 2);
    unsigned short* xb    = (unsigned short*)alloc((size_t)2048 * 2048 * 2);
    float*          ML    = (float*)alloc((size_t)512 * 128 * 2 * 4);
    unsigned short* attn  = (unsigned short*)alloc((size_t)NH * S_LEN * HD * 2);
    float*          Opart = (float*)alloc((size_t)512 * 128 * 64 * 4);
    unsigned short* h2 = xb;  // reuses xb (x dead after QKV gemm)

    cast_bf16_kernel<<<2048, 256, 0, stream>>>(x, xb, 2048 * 2048);
    prep_transpose_kernel<<<dim3(64, 64, 5), dim3(32, 8), 0, stream>>>(
        wq, wk, wv, wo, fw, wqkvT, woT, fwT);

    // QKV GEMM with fused RoPE/V-transpose epilogue -> Qb, Kb, VT
    gemm_bt_kernel<1><<<dim3(16, 48), 256, 0, stream>>>(
        xb, wqkvT, nullptr, Qb, Kb, VT, fcos, fsin, 2048, 3072, 2048);

    flash_kernel<<<768, 256, 0, stream>>>(Qb, Kb, VT, attn, Opart, ML);
    flash_combine_kernel<<<256, 256, 0, stream>>>(Opart, ML, attn);

    fw_silu_kernel<<<1024, 256, 0, stream>>>(attn, fwT, fb, h2);

    // wo GEMM: 128x64 tiles -> 512 blocks (2/CU uniform), fp32 out, full K
    gemm_bt_kernel<0><<<dim3(16, 32), 256, 0, stream>>>(
        h2, woT, out, nullptr, nullptr, nullptr, nullptr, nullptr,
        2048, 2048, 2048);
}